// Round 1
// 616.935 us; speedup vs baseline: 1.3112x; 1.3112x over previous
//
#include <hip/hip_runtime.h>
#include <math.h>

#define BB 4
#define UU 512
#define DD 80
#define HH 8
#define FFND 2048
#define LL 12
#define SEGC 32
#define LCC 50
#define RCC 8
#define NSEG 16
#define RCL 128
#define KK 640
#define ROWS (BB*KK)        // 2560
#define OUTD 768
#define NSPLIT 8
#define EPSF 1e-5f
#define SCALEF 0.31622776601683794f  // (D/H)^-0.5 = 10^-0.5

typedef __attribute__((ext_vector_type(8))) short bf16x8;
typedef __attribute__((ext_vector_type(4))) float f32x4;

__device__ inline unsigned short f2bf(float f) {
  unsigned int u = __float_as_uint(f);
  u += 0x7fffu + ((u >> 16) & 1u);
  return (unsigned short)(u >> 16);
}

// ---------------- gather: x0 = concat(rc, utt) ----------------
__global__ __launch_bounds__(256) void k_gather(const float* __restrict__ mel,
                                                float* __restrict__ x) {
  int idx = blockIdx.x * 256 + threadIdx.x;
  if (idx >= ROWS * DD) return;
  int d = idx % DD;
  int row = idx / DD;
  int b = row / KK;
  int j = row % KK;
  int pos;
  if (j < RCL) {
    int i = j >> 3, r = j & 7;
    pos = (i < NSEG - 1) ? (i + 1) * SEGC + r : UU + r;
  } else {
    pos = j - RCL;
  }
  x[idx] = mel[(b * (UU + RCC) + pos) * DD + d];
}

// ---------------- convert W1/W2 (all layers) fp32 -> bf16 ----------------
__global__ __launch_bounds__(256) void k_cvt(const float* __restrict__ W1,
                                             const float* __restrict__ W2,
                                             unsigned short* __restrict__ o1,
                                             unsigned short* __restrict__ o2) {
  const int NV = (LL * FFND * DD) / 4;  // float4 count per tensor
  int t = blockIdx.x * 256 + threadIdx.x;
  const float* src;
  unsigned short* dst;
  int i;
  if (t < NV) { src = W1; dst = o1; i = t; }
  else        { src = W2; dst = o2; i = t - NV; }
  float4 v = reinterpret_cast<const float4*>(src)[i];
  ushort4 r;
  r.x = f2bf(v.x); r.y = f2bf(v.y); r.z = f2bf(v.z); r.w = f2bf(v.w);
  reinterpret_cast<ushort4*>(dst)[i] = r;
}

// ---------------- A: LN_in fused + QKV GEMM (fp32) ----------------
__global__ __launch_bounds__(256) void k_qkv(
    const float* __restrict__ x, float* __restrict__ qkv,
    const float* __restrict__ Wq, const float* __restrict__ bq,
    const float* __restrict__ Wkv, const float* __restrict__ bkv,
    const float* __restrict__ lg, const float* __restrict__ lb) {
  __shared__ float s_x[32 * 84];
  __shared__ float s_w[80 * 84];
  __shared__ float s_mu[32], s_ri[32];
  int tid = threadIdx.x;
  int r0 = blockIdx.x * 32;
  int ct = blockIdx.y;
  for (int k = 0; k < 3; ++k) {
    int idx = tid + k * 256;
    if (idx < 640) {
      int row = idx / 20, c4 = idx % 20;
      *reinterpret_cast<float4*>(&s_x[row * 84 + c4 * 4]) =
          *reinterpret_cast<const float4*>(&x[(r0 + row) * DD + c4 * 4]);
    }
  }
  const float* Wbase = (ct == 0) ? Wq : (ct == 1 ? Wkv : (Wkv + 80 * DD));
  for (int k = 0; k < 7; ++k) {
    int idx = tid + k * 256;
    if (idx < 1600) {
      int c = idx / 20, d4 = idx % 20;
      *reinterpret_cast<float4*>(&s_w[c * 84 + d4 * 4]) =
          *reinterpret_cast<const float4*>(&Wbase[c * DD + d4 * 4]);
    }
  }
  __syncthreads();
  {
    int rr = tid >> 3, t8 = tid & 7;
    float sm = 0.f, sq = 0.f;
    for (int d = t8 * 10; d < t8 * 10 + 10; ++d) {
      float v = s_x[rr * 84 + d];
      sm += v; sq += v * v;
    }
    for (int m = 4; m >= 1; m >>= 1) {
      sm += __shfl_xor(sm, m, 8);
      sq += __shfl_xor(sq, m, 8);
    }
    if (t8 == 0) {
      float mu = sm * (1.f / DD);
      float var = sq * (1.f / DD) - mu * mu;
      s_mu[rr] = mu;
      s_ri[rr] = rsqrtf(var + EPSF);
    }
  }
  __syncthreads();
  for (int k = 0; k < 10; ++k) {
    int e = tid + k * 256;
    int row = e / 80, d = e % 80;
    s_x[row * 84 + d] = (s_x[row * 84 + d] - s_mu[row]) * s_ri[row] * lg[d] + lb[d];
  }
  __syncthreads();
  int ty = tid >> 4, tx = tid & 15;
  float acc[2][5] = {};
  for (int d4 = 0; d4 < 20; ++d4) {
    float4 a0 = *reinterpret_cast<const float4*>(&s_x[(2 * ty) * 84 + d4 * 4]);
    float4 a1 = *reinterpret_cast<const float4*>(&s_x[(2 * ty + 1) * 84 + d4 * 4]);
#pragma unroll
    for (int j = 0; j < 5; ++j) {
      float4 w = *reinterpret_cast<const float4*>(&s_w[(tx + 16 * j) * 84 + d4 * 4]);
      acc[0][j] += a0.x * w.x + a0.y * w.y + a0.z * w.z + a0.w * w.w;
      acc[1][j] += a1.x * w.x + a1.y * w.y + a1.z * w.z + a1.w * w.w;
    }
  }
  const float* bias = (ct == 0) ? bq : (bkv + (ct == 2 ? 80 : 0));
  for (int i2 = 0; i2 < 2; ++i2)
    for (int j = 0; j < 5; ++j) {
      int c = tx + 16 * j;
      int grow = r0 + 2 * ty + i2;
      qkv[grow * 240 + ct * 80 + c] = acc[i2][j] + bias[c];
    }
}

// ---------------- B: masked segmented attention (256 thr, parallel softmax) --
__global__ __launch_bounds__(256) void k_attn(const float* __restrict__ qkv,
                                              float* __restrict__ attn,
                                              const int* __restrict__ lengths) {
  int i = blockIdx.x, h = blockIdx.y, b = blockIdx.z;
  int tid = threadIdx.x;
  int s = i * SEGC - LCC; if (s < 0) s = 0;
  int e = (i + 1) * SEGC;
  int nk = RCC + (e - s);  // <= 90
  __shared__ float s_k[90 * 10], s_v[90 * 10], s_q[40 * 10];
  __shared__ float s_p[40 * 90], s_kb[90], s_den[40];
  int len = lengths[b];
  if (tid < 90 && tid < nk) {
    int j = tid;
    int kr = (j < RCC) ? i * RCC + j : RCL + s + (j - RCC);
    const float* kp = &qkv[(b * KK + kr) * 240 + 80 + h * 10];
    const float* vp = &qkv[(b * KK + kr) * 240 + 160 + h * 10];
#pragma unroll
    for (int d = 0; d < 10; ++d) { s_k[j * 10 + d] = kp[d]; s_v[j * 10 + d] = vp[d]; }
    s_kb[j] = (kr >= len + RCL) ? -1e8f : 0.f;
  }
  if (tid >= 128 && tid < 168) {
    int j = tid - 128;
    int qr = (j < RCC) ? i * RCC + j : RCL + i * SEGC + (j - RCC);
    const float* qp = &qkv[(b * KK + qr) * 240 + h * 10];
#pragma unroll
    for (int d = 0; d < 10; ++d) s_q[j * 10 + d] = qp[d];
  }
  __syncthreads();
  for (int p = tid; p < 3600; p += 256) {
    int q = p / 90, jk = p % 90;
    float sc = -1e30f;
    if (jk < nk) {
      float dot = 0.f;
#pragma unroll
      for (int d = 0; d < 10; ++d) dot += s_q[q * 10 + d] * s_k[jk * 10 + d];
      sc = dot * SCALEF + s_kb[jk];
    }
    s_p[p] = sc;
  }
  __syncthreads();
  if (tid < 160) {
    int r = tid >> 2, l4 = tid & 3;
    float m = -1e30f;
    for (int kx = l4; kx < 90; kx += 4) m = fmaxf(m, s_p[r * 90 + kx]);
    m = fmaxf(m, __shfl_xor(m, 1, 4));
    m = fmaxf(m, __shfl_xor(m, 2, 4));
    float sum = 0.f;
    for (int kx = l4; kx < 90; kx += 4) {
      float ev = __expf(s_p[r * 90 + kx] - m);
      s_p[r * 90 + kx] = ev;
      sum += ev;
    }
    sum += __shfl_xor(sum, 1, 4);
    sum += __shfl_xor(sum, 2, 4);
    if (l4 == 0) s_den[r] = sum;
  }
  __syncthreads();
  for (int po = tid; po < 400; po += 256) {
    int q = po / 10, d = po % 10;
    float o = 0.f;
    for (int kx = 0; kx < 90; ++kx) o += s_p[q * 90 + kx] * s_v[kx * 10 + d];
    int qr = (q < RCC) ? i * RCC + q : RCL + i * SEGC + (q - RCC);
    attn[(b * KK + qr) * DD + h * 10 + d] = o / s_den[q];
  }
}

// ---------------- C: out-proj + bias + residual + LN_ff (writes bf16 ffln) ----
__global__ __launch_bounds__(256) void k_oproj(
    const float* __restrict__ attn, const float* __restrict__ Wo,
    const float* __restrict__ bo, const float* __restrict__ x,
    float* __restrict__ res, unsigned short* __restrict__ ffln_bf,
    const float* __restrict__ fg, const float* __restrict__ fb) {
  __shared__ float s_at[16 * 84], s_x2[16 * 84], s_wo[80 * 84];
  int tid = threadIdx.x;
  int r0 = blockIdx.x * 16;
  for (int k = 0; k < 2; ++k) {
    int idx = tid + k * 256;
    if (idx < 320) {
      int row = idx / 20, c4 = idx % 20;
      *reinterpret_cast<float4*>(&s_at[row * 84 + c4 * 4]) =
          *reinterpret_cast<const float4*>(&attn[(r0 + row) * DD + c4 * 4]);
      *reinterpret_cast<float4*>(&s_x2[row * 84 + c4 * 4]) =
          *reinterpret_cast<const float4*>(&x[(r0 + row) * DD + c4 * 4]);
    }
  }
  for (int k = 0; k < 7; ++k) {
    int idx = tid + k * 256;
    if (idx < 1600) {
      int c = idx / 20, d4 = idx % 20;
      *reinterpret_cast<float4*>(&s_wo[c * 84 + d4 * 4]) =
          *reinterpret_cast<const float4*>(&Wo[c * DD + d4 * 4]);
    }
  }
  __syncthreads();
  int r = tid >> 4, tx = tid & 15;
  float acc[5] = {};
  for (int d4 = 0; d4 < 20; ++d4) {
    float4 a = *reinterpret_cast<const float4*>(&s_at[r * 84 + d4 * 4]);
#pragma unroll
    for (int j = 0; j < 5; ++j) {
      float4 w = *reinterpret_cast<const float4*>(&s_wo[(tx + 16 * j) * 84 + d4 * 4]);
      acc[j] += a.x * w.x + a.y * w.y + a.z * w.z + a.w * w.w;
    }
  }
  float val[5];
  float sm = 0.f, sq = 0.f;
#pragma unroll
  for (int j = 0; j < 5; ++j) {
    int c = tx + 16 * j;
    float v = acc[j] + bo[c] + s_x2[r * 84 + c];
    val[j] = v;
    res[(r0 + r) * DD + c] = v;
    sm += v; sq += v * v;
  }
  for (int m = 8; m >= 1; m >>= 1) {
    sm += __shfl_xor(sm, m, 16);
    sq += __shfl_xor(sq, m, 16);
  }
  float mu = sm * (1.f / DD);
  float ri = rsqrtf(sq * (1.f / DD) - mu * mu + EPSF);
#pragma unroll
  for (int j = 0; j < 5; ++j) {
    int c = tx + 16 * j;
    ffln_bf[(r0 + r) * DD + c] = f2bf((val[j] - mu) * ri * fg[c] + fb[c]);
  }
}

// ---------------- D: fused FFN (relu(ffln@W1^T+b1) @ W2^T), h stays in LDS ---
// grid (ROWS/64, NSPLIT), block 256. Each split covers 256 ffn cols
// processed as 2 chunks of 128. K=80 zero-padded to 96 for FFN1.
__global__ __launch_bounds__(256) void k_ffn(
    const unsigned short* __restrict__ A, const unsigned short* __restrict__ W1,
    const float* __restrict__ b1, const unsigned short* __restrict__ W2,
    float* __restrict__ part) {
  __shared__ unsigned short s_a[64 * 104];    // ffln tile, K-pad to 96
  __shared__ unsigned short s_w1[128 * 104];  // W1 chunk, K-pad to 96
  __shared__ unsigned short s_h[64 * 136];    // relu(h) tile, K=128 exact
  __shared__ unsigned short s_w2[80 * 136];   // W2 chunk
  int tid = threadIdx.x;
  int r0 = blockIdx.x * 64;
  int F0 = blockIdx.y * 256;
  int w = tid >> 6, lane = tid & 63;
  int m = lane & 15, q = lane >> 4;

  // stage A once: 64 rows x 10 chunks of 8 bf16 = 640
  for (int k = 0; k < 3; ++k) {
    int idx = tid + k * 256;
    if (idx < 640) {
      int row = idx / 10, ch = idx % 10;
      *reinterpret_cast<uint4*>(&s_a[row * 104 + ch * 8]) =
          *reinterpret_cast<const uint4*>(&A[(r0 + row) * DD + ch * 8]);
    }
  }
  if (tid < 128) {  // zero K-pad 80..95 of s_a
    int row = tid >> 1, half = tid & 1;
    uint4 z = make_uint4(0, 0, 0, 0);
    *reinterpret_cast<uint4*>(&s_a[row * 104 + 80 + half * 8]) = z;
  }
  // stage W1/W2 chunk 0
  {
    int fc0 = F0;
    for (int k = 0; k < 5; ++k) {
      int idx = tid + k * 256;  // 1280 = 128 rows x 10
      int row = idx / 10, ch = idx % 10;
      *reinterpret_cast<uint4*>(&s_w1[row * 104 + ch * 8]) =
          *reinterpret_cast<const uint4*>(&W1[(fc0 + row) * DD + ch * 8]);
    }
    {  // zero K-pad of s_w1: 128 rows x 2 halves = 256
      int row = tid >> 1, half = tid & 1;
      uint4 z = make_uint4(0, 0, 0, 0);
      *reinterpret_cast<uint4*>(&s_w1[row * 104 + 80 + half * 8]) = z;
    }
    for (int k = 0; k < 5; ++k) {
      int idx = tid + k * 256;  // 1280 = 80 rows x 16
      int row = idx >> 4, ch = idx & 15;
      *reinterpret_cast<uint4*>(&s_w2[row * 136 + ch * 8]) =
          *reinterpret_cast<const uint4*>(&W2[row * FFND + fc0 + ch * 8]);
    }
  }
  __syncthreads();

  f32x4 acc2[5] = {};
  for (int c = 0; c < 2; ++c) {
    int fc0 = F0 + c * 128;
    // FFN1: wave w computes rows w*16..w*16+16 x 128 ffn cols
    f32x4 acc1[8] = {};
#pragma unroll
    for (int kk = 0; kk < 3; ++kk) {
      bf16x8 a = *reinterpret_cast<const bf16x8*>(&s_a[(w * 16 + m) * 104 + kk * 32 + q * 8]);
#pragma unroll
      for (int ct = 0; ct < 8; ++ct) {
        bf16x8 b = *reinterpret_cast<const bf16x8*>(&s_w1[(ct * 16 + m) * 104 + kk * 32 + q * 8]);
        acc1[ct] = __builtin_amdgcn_mfma_f32_16x16x32_bf16(a, b, acc1[ct], 0, 0, 0);
      }
    }
    // relu + bias -> bf16 -> s_h (C layout: col=lane&15, row=q*4+r)
#pragma unroll
    for (int ct = 0; ct < 8; ++ct) {
      int col = ct * 16 + m;
      float bias = b1[fc0 + col];
#pragma unroll
      for (int r = 0; r < 4; ++r) {
        int row = w * 16 + q * 4 + r;
        s_h[row * 136 + col] = f2bf(fmaxf(acc1[ct][r] + bias, 0.f));
      }
    }
    __syncthreads();
    // FFN2: acc2 += s_h(64x128) @ s_w2(80x128)^T
#pragma unroll
    for (int kk = 0; kk < 4; ++kk) {
      bf16x8 a = *reinterpret_cast<const bf16x8*>(&s_h[(w * 16 + m) * 136 + kk * 32 + q * 8]);
#pragma unroll
      for (int ct = 0; ct < 5; ++ct) {
        bf16x8 b = *reinterpret_cast<const bf16x8*>(&s_w2[(ct * 16 + m) * 136 + kk * 32 + q * 8]);
        acc2[ct] = __builtin_amdgcn_mfma_f32_16x16x32_bf16(a, b, acc2[ct], 0, 0, 0);
      }
    }
    __syncthreads();
    if (c == 0) {  // stage W1/W2 chunk 1 (s_w1/s_w2 now dead)
      int fn = F0 + 128;
      for (int k = 0; k < 5; ++k) {
        int idx = tid + k * 256;
        int row = idx / 10, ch = idx % 10;
        *reinterpret_cast<uint4*>(&s_w1[row * 104 + ch * 8]) =
            *reinterpret_cast<const uint4*>(&W1[(fn + row) * DD + ch * 8]);
      }
      for (int k = 0; k < 5; ++k) {
        int idx = tid + k * 256;
        int row = idx >> 4, ch = idx & 15;
        *reinterpret_cast<uint4*>(&s_w2[row * 136 + ch * 8]) =
            *reinterpret_cast<const uint4*>(&W2[row * FFND + fn + ch * 8]);
      }
      __syncthreads();
    }
  }
#pragma unroll
  for (int ct = 0; ct < 5; ++ct)
#pragma unroll
    for (int r = 0; r < 4; ++r) {
      int grow = r0 + w * 16 + q * 4 + r;
      part[blockIdx.y * (ROWS * DD) + grow * DD + ct * 16 + m] = acc2[ct][r];
    }
}

// ---------------- F: combine splits + b2 + residual + LN_out -> x ------------
__global__ __launch_bounds__(128) void k_comb(
    const float* __restrict__ part, const float* __restrict__ b2,
    const float* __restrict__ res, float* __restrict__ x,
    const float* __restrict__ og, const float* __restrict__ ob) {
  int row = blockIdx.x;
  int t = threadIdx.x;
  __shared__ float rsum[128], rsq[128];
  float v = 0.f;
  if (t < DD) {
#pragma unroll
    for (int s = 0; s < NSPLIT; ++s) v += part[s * (ROWS * DD) + row * DD + t];
    v += b2[t] + res[row * DD + t];
  }
  rsum[t] = (t < DD) ? v : 0.f;
  rsq[t] = (t < DD) ? v * v : 0.f;
  __syncthreads();
  for (int m2 = 64; m2 >= 1; m2 >>= 1) {
    if (t < m2) { rsum[t] += rsum[t + m2]; rsq[t] += rsq[t + m2]; }
    __syncthreads();
  }
  float mu = rsum[0] * (1.f / DD);
  float ri = rsqrtf(rsq[0] * (1.f / DD) - mu * mu + EPSF);
  if (t < DD) x[row * DD + t] = (v - mu) * ri * og[t] + ob[t];
}

// ---------------- P: final projection + lengths tail ----------------
__global__ __launch_bounds__(256) void k_proj(
    const float* __restrict__ x, const float* __restrict__ Wp,
    const float* __restrict__ bp, const int* __restrict__ lengths,
    float* __restrict__ out) {
  __shared__ float s_a[64 * 84], s_w[64 * 84];
  int tid = threadIdx.x;
  int gr0 = blockIdx.x * 64;
  int c0 = blockIdx.y * 64;
  int b = gr0 / UU;
  int u0 = gr0 % UU;
  for (int k = 0; k < 5; ++k) {
    int idx = tid + k * 256;
    int row = idx / 20, c4 = idx % 20;
    *reinterpret_cast<float4*>(&s_a[row * 84 + c4 * 4]) =
        *reinterpret_cast<const float4*>(&x[(b * KK + RCL + u0 + row) * DD + c4 * 4]);
    *reinterpret_cast<float4*>(&s_w[row * 84 + c4 * 4]) =
        *reinterpret_cast<const float4*>(&Wp[(c0 + row) * DD + c4 * 4]);
  }
  __syncthreads();
  int ty = tid >> 4, tx = tid & 15;
  float acc[4][4] = {};
  for (int d4 = 0; d4 < 20; ++d4) {
    float4 a[4], w[4];
#pragma unroll
    for (int i2 = 0; i2 < 4; ++i2)
      a[i2] = *reinterpret_cast<const float4*>(&s_a[(4 * ty + i2) * 84 + d4 * 4]);
#pragma unroll
    for (int j = 0; j < 4; ++j)
      w[j] = *reinterpret_cast<const float4*>(&s_w[(tx + 16 * j) * 84 + d4 * 4]);
#pragma unroll
    for (int i2 = 0; i2 < 4; ++i2)
#pragma unroll
      for (int j = 0; j < 4; ++j)
        acc[i2][j] += a[i2].x * w[j].x + a[i2].y * w[j].y +
                      a[i2].z * w[j].z + a[i2].w * w[j].w;
  }
  for (int i2 = 0; i2 < 4; ++i2)
    for (int j = 0; j < 4; ++j) {
      int c = c0 + tx + 16 * j;
      out[(gr0 + 4 * ty + i2) * OUTD + c] = acc[i2][j] + bp[c];
    }
  if (blockIdx.x == 0 && blockIdx.y == 0 && tid < BB)
    out[BB * UU * OUTD + tid] = (float)lengths[tid];
}

extern "C" void kernel_launch(void* const* d_in, const int* in_sizes, int n_in,
                              void* d_out, int out_size, void* d_ws, size_t ws_size,
                              hipStream_t stream) {
  const float* mel   = (const float*)d_in[0];
  const float* lng   = (const float*)d_in[1];
  const float* lnb   = (const float*)d_in[2];
  const float* Wq    = (const float*)d_in[3];
  const float* bq    = (const float*)d_in[4];
  const float* Wkv   = (const float*)d_in[5];
  const float* bkv   = (const float*)d_in[6];
  const float* Wo    = (const float*)d_in[7];
  const float* bo    = (const float*)d_in[8];
  const float* ffg   = (const float*)d_in[9];
  const float* ffb   = (const float*)d_in[10];
  const float* W1    = (const float*)d_in[11];
  const float* b1    = (const float*)d_in[12];
  const float* W2    = (const float*)d_in[13];
  const float* b2    = (const float*)d_in[14];
  const float* og    = (const float*)d_in[15];
  const float* ob    = (const float*)d_in[16];
  const float* Wp    = (const float*)d_in[17];
  const float* bp    = (const float*)d_in[18];
  const int*   lens  = (const int*)d_in[19];
  float* out = (float*)d_out;

  // workspace layout (floats); part aliases qkv (qkv dead after k_attn,
  // part written by k_ffn afterwards, dead before next layer's k_qkv)
  float* ws   = (float*)d_ws;
  float* x    = ws;                          // 204800
  float* qkv  = x + ROWS * DD;               // aliased region: 8*204800
  float* part = qkv;
  float* attn = qkv + NSPLIT * ROWS * DD;    // 204800
  float* res  = attn + ROWS * DD;            // 204800
  unsigned short* ffln_bf = (unsigned short*)(res + ROWS * DD);          // ROWS*80 bf16
  unsigned short* w1bf    = ffln_bf + ROWS * DD;                         // 12*2048*80 bf16
  unsigned short* w2bf    = w1bf + LL * FFND * DD;                       // 12*2048*80 bf16

  k_gather<<<(ROWS * DD + 255) / 256, 256, 0, stream>>>(mel, x);
  k_cvt<<<(2 * (LL * FFND * DD) / 4 + 255) / 256, 256, 0, stream>>>(W1, W2, w1bf, w2bf);

  for (int l = 0; l < LL; ++l) {
    const float* lWq  = Wq  + l * DD * DD;
    const float* lbq  = bq  + l * DD;
    const float* lWkv = Wkv + l * 2 * DD * DD;
    const float* lbkv = bkv + l * 2 * DD;
    const float* lWo  = Wo  + l * DD * DD;
    const float* lbo  = bo  + l * DD;
    const unsigned short* lW1 = w1bf + l * FFND * DD;
    const float* lb1  = b1  + l * FFND;
    const unsigned short* lW2 = w2bf + l * FFND * DD;
    const float* lb2  = b2  + l * DD;

    k_qkv<<<dim3(ROWS / 32, 3), 256, 0, stream>>>(
        x, qkv, lWq, lbq, lWkv, lbkv, lng + l * DD, lnb + l * DD);
    k_attn<<<dim3(NSEG, HH, BB), 256, 0, stream>>>(qkv, attn, lens);
    k_oproj<<<ROWS / 16, 256, 0, stream>>>(
        attn, lWo, lbo, x, res, ffln_bf, ffg + l * DD, ffb + l * DD);
    k_ffn<<<dim3(ROWS / 64, NSPLIT), 256, 0, stream>>>(ffln_bf, lW1, lb1, lW2, part);
    k_comb<<<ROWS, 128, 0, stream>>>(part, lb2, res, x, og + l * DD, ob + l * DD);
  }

  k_proj<<<dim3(BB * UU / 64, OUTD / 64), 256, 0, stream>>>(x, Wp, bp, lens, out);
}